// Round 4
// baseline (381.858 us; speedup 1.0000x reference)
//
#include <hip/hip_runtime.h>

// Shift_DWConv: depthwise 3x3 conv with power-of-two (DeepShift) weights.
// x: [B=16, N=4096, C=768] f32 channels-last; out same.
// Memory-bound: ideal HBM traffic = 201 MB read + 201 MB write ~ 64 us floor.

#define DIM 768
#define HD  64
#define WD  64
#define BD  16
#define TH  8          // output rows per block (rolling-register h-sweep)
#define NPIX (HD * WD)

typedef float f32x4 __attribute__((ext_vector_type(4)));

__device__ __forceinline__ float qfix(float x) {
    // round_to_fixed: floor(x * 2^16) * 2^-16, clipped to [-2^15, 2^15 - 1]
    float v = floorf(x * 65536.0f) * 1.52587890625e-05f;
    return fminf(fmaxf(v, -32768.0f), 32767.0f);
}

__device__ __forceinline__ float4 zero4() { return make_float4(0.f, 0.f, 0.f, 0.f); }

__device__ __forceinline__ float4 q4(float4 v) {
    v.x = qfix(v.x); v.y = qfix(v.y); v.z = qfix(v.z); v.w = qfix(v.w);
    return v;
}

__device__ __forceinline__ float4 fma4(float4 a, float4 b, float4 c) {
    c.x = fmaf(a.x, b.x, c.x);
    c.y = fmaf(a.y, b.y, c.y);
    c.z = fmaf(a.z, b.z, c.z);
    c.w = fmaf(a.w, b.w, c.w);
    return c;
}

// Pre-kernel: dequantize power-of-two weights once into ws as [9][768]
// (tap-major so the main kernel's per-tap float4 loads coalesce), and
// fixed-point-quantize bias.
__global__ void wprep_kernel(const float* __restrict__ shift,
                             const float* __restrict__ sgn,
                             const float* __restrict__ bias,
                             float* __restrict__ wbuf,
                             float* __restrict__ bbuf) {
    int i = blockIdx.x * 256 + threadIdx.x;
    if (i < DIM * 9) {
        int c = i / 9;
        int k = i - c * 9;                       // input layout [C][3][3]
        float sr = rintf(fminf(fmaxf(shift[i], -14.0f), 0.0f)); // round(clip(shift))
        float g  = rintf(sgn[i]);                // round(sign_param)
        float sg = (g > 0.0f) ? 1.0f : ((g < 0.0f) ? -1.0f : 0.0f); // sign()
        wbuf[k * DIM + c] = exp2f(sr) * sg;      // 2^shift_r * sign_r
    }
    if (i < DIM) bbuf[i] = qfix(bias[i]);
}

struct Row { float4 l, m, r; };

__device__ __forceinline__ Row load_row(const float* p, bool valid, bool wl, bool wr) {
    Row r;
    if (valid) {
        r.m = q4(*(const float4*)p);
        r.l = wl ? q4(*(const float4*)(p - DIM)) : zero4();
        r.r = wr ? q4(*(const float4*)(p + DIM)) : zero4();
    } else {
        r.l = zero4(); r.m = zero4(); r.r = zero4();
    }
    return r;
}

// One block = one (batch, w-column, 8-row h-strip), 192 threads x float4 = 768 ch.
// Rolling registers along h: each output row needs only 3 new float4 loads.
__global__ __launch_bounds__(192) void dwconv_kernel(
        const float* __restrict__ x,
        const float* __restrict__ wbuf,
        const float* __restrict__ bbuf,
        float* __restrict__ out) {
    const int c  = threadIdx.x * 4;
    const int w  = blockIdx.x;
    const int h0 = blockIdx.y * TH;
    const int b  = blockIdx.z;

    float4 wk[9];
    #pragma unroll
    for (int k = 0; k < 9; ++k)
        wk[k] = *(const float4*)(wbuf + k * DIM + c);
    const float4 bq = *(const float4*)(bbuf + c);

    const bool wl = (w > 0), wr = (w < WD - 1);
    const float* xb = x   + ((size_t)b * NPIX + w) * DIM + c;
    float*       ob = out + ((size_t)b * NPIX + w) * DIM + c;
    const long rowstride = (long)WD * DIM;

    Row r0 = load_row(xb + (long)(h0 - 1) * rowstride, h0 > 0, wl, wr);
    Row r1 = load_row(xb + (long)h0 * rowstride, true, wl, wr);

    #pragma unroll
    for (int hh = 0; hh < TH; ++hh) {
        const int h = h0 + hh;
        Row r2 = load_row(xb + (long)(h + 1) * rowstride, (h + 1) < HD, wl, wr);
        float4 acc = bq;
        // XLA conv_general_dilated = cross-correlation: tap k = ky*3+kx hits
        // input row h-1+ky, col w-1+kx.
        acc = fma4(wk[0], r0.l, acc);
        acc = fma4(wk[1], r0.m, acc);
        acc = fma4(wk[2], r0.r, acc);
        acc = fma4(wk[3], r1.l, acc);
        acc = fma4(wk[4], r1.m, acc);
        acc = fma4(wk[5], r1.r, acc);
        acc = fma4(wk[6], r2.l, acc);
        acc = fma4(wk[7], r2.m, acc);
        acc = fma4(wk[8], r2.r, acc);
        // Output is write-once: nontemporal store keeps the 201 MB write
        // stream from evicting input lines that neighbor blocks re-read.
        // (builtin needs a clang ext_vector_type, not HIP's float4 class)
        f32x4 av; av.x = acc.x; av.y = acc.y; av.z = acc.z; av.w = acc.w;
        __builtin_nontemporal_store(av, (f32x4*)(ob + (long)h * rowstride));
        r0 = r1; r1 = r2;
    }
}

extern "C" void kernel_launch(void* const* d_in, const int* in_sizes, int n_in,
                              void* d_out, int out_size, void* d_ws, size_t ws_size,
                              hipStream_t stream) {
    const float* x     = (const float*)d_in[0];
    const float* shift = (const float*)d_in[1];
    const float* sgn   = (const float*)d_in[2];
    const float* bias  = (const float*)d_in[3];
    // d_in[4] = H, d_in[5] = W (compile-time constants here)
    float* out  = (float*)d_out;
    float* wbuf = (float*)d_ws;        // 9*768 floats
    float* bbuf = wbuf + 9 * DIM;      // 768 floats  (total 30 KB < ws_size)

    wprep_kernel<<<(DIM * 9 + 255) / 256, 256, 0, stream>>>(shift, sgn, bias, wbuf, bbuf);

    dim3 grid(WD, HD / TH, BD);
    dwconv_kernel<<<grid, 192, 0, stream>>>(x, wbuf, bbuf, out);
}